// Round 7
// baseline (273.689 us; speedup 1.0000x reference)
//
#include <hip/hip_runtime.h>
#include <hip/hip_bf16.h>

#define NN 100000
#define NE 1000000
#define HD 64
#define NB 98                       // dst buckets of 1024 nodes
#define BSH 10
#define BCAP 12288                  // bin capacity (avg 10240, +20 sigma)
#define EPB 8192                    // edges per k_bin block
#define NB1 ((NE + EPB - 1) / EPB)  // 123
#define NSTR (NN + 1)               // per-slab node stride (row NN = dummy zeros)
#define NBATCH ((NN + 255) / 256)   // 391 batches of 256 nodes

typedef unsigned short u16;
typedef unsigned int u32;
typedef unsigned long long u64;

__device__ __forceinline__ u16 f2b(float f) {
    __hip_bfloat16 h = __float2bfloat16(f);   // RNE
    return *reinterpret_cast<u16*>(&h);
}
__device__ __forceinline__ float uaf(u32 u) { return __uint_as_float(u); }

// ---------------- CSR build: bucketed counting sort (u32-packed bins) ----------------

__global__ __launch_bounds__(256) void k_bin(const int* __restrict__ ei,
                                             int* __restrict__ bfill,
                                             u32* __restrict__ bins) {
    __shared__ int hist[NB];
    __shared__ int base[NB];
    int tid = threadIdx.x;
    for (int i = tid; i < NB; i += 256) hist[i] = 0;
    __syncthreads();
    int e0 = blockIdx.x * EPB;
    int n = min(EPB, NE - e0);
    for (int i = tid; i < n; i += 256)
        atomicAdd(&hist[ei[NE + e0 + i] >> BSH], 1);
    __syncthreads();
    for (int i = tid; i < NB; i += 256) {
        int c = hist[i];
        base[i] = c ? atomicAdd(&bfill[i], c) : 0;
        hist[i] = 0;
    }
    __syncthreads();
    for (int i = tid; i < n; i += 256) {
        int s = ei[e0 + i];
        int d = ei[NE + e0 + i];
        int g = d >> BSH;
        int pos = base[g] + atomicAdd(&hist[g], 1);
        bins[(size_t)g * BCAP + min(pos, BCAP - 1)] = ((u32)(d & 1023) << 17) | (u32)s;
    }
}

// per bucket: base (from bfill), rowptr, self-loop, dis, xs, XCD-local edge scatter,
// and T dummy-row zeroing. Unpadded CSR: row len = cnt+1. col stores src INDEX.
__global__ __launch_bounds__(1024) void k_build(const u32* __restrict__ bins,
        const int* __restrict__ bfill,
        int* __restrict__ rowptr, int* __restrict__ col,
        const float2* __restrict__ x2, float* __restrict__ dis,
        float2* __restrict__ xs, u16* __restrict__ T) {
    __shared__ int cnt[1024];
    __shared__ int rof[1024];
    __shared__ int wsum[16];
    __shared__ int gbase_sh;
    int g = blockIdx.x, tid = threadIdx.x;
    int lane = tid & 63, w = tid >> 6;

    // bucket base = sum_{t<g} (bfill[t] + 1024 self-loops)
    int part = (tid < g) ? (bfill[tid] + 1024) : 0;
#pragma unroll
    for (int off = 32; off; off >>= 1) part += __shfl_xor(part, off);
    if (lane == 0) wsum[w] = part;
    cnt[tid] = 0;
    __syncthreads();
    if (tid == 0) {
        int s = 0;
#pragma unroll
        for (int i = 0; i < 16; ++i) s += wsum[i];
        gbase_sh = s;
        if (g == NB - 1) rowptr[NN] = s + bfill[g] + (NN - (NB - 1) * 1024);
    }
    __syncthreads();
    int gbase = gbase_sh;

    int n = min(bfill[g], BCAP);
    const u32* bp = bins + (size_t)g * BCAP;
    for (int i = tid; i < n; i += 1024)
        atomicAdd(&cnt[bp[i] >> 17], 1);
    __syncthreads();

    int node = (g << BSH) + tid;
    int c = cnt[tid];
    int pc = (node < NN) ? (c + 1) : 0;

    int s = pc;
#pragma unroll
    for (int off = 1; off < 64; off <<= 1) { int t = __shfl_up(s, off); if (lane >= off) s += t; }
    if (lane == 63) wsum[w] = s;
    __syncthreads();
    if (tid < 16) {
        int ws = wsum[tid];
#pragma unroll
        for (int off = 1; off < 16; off <<= 1) { int t = __shfl_up(ws, off); if (tid >= off) ws += t; }
        wsum[tid] = ws;
    }
    __syncthreads();
    int r = gbase + (w ? wsum[w - 1] : 0) + s - pc;
    rof[tid] = r;
    if (node < NN) {
        rowptr[node] = r;
        col[r] = node;                    // self-loop at slot 0
        float dd = rsqrtf((float)(c + 1));
        dis[node] = dd;
        float2 xv = x2[node];
        xs[node] = make_float2(xv.x * dd, xv.y * dd);
    }
    cnt[tid] = 1;                         // fill counter (slot 0 taken)
    __syncthreads();

    for (int i = tid; i < n; i += 1024) {
        u32 v = bp[i];
        int dloc = v >> 17;
        int src = (int)(v & 0x1ffffu);
        int local = atomicAdd(&cnt[dloc], 1);
        col[rof[dloc] + local] = src;
    }

    if (g == 0) {
        if (tid < 64) T[(size_t)((tid >> 3) * NSTR + NN) * 8 + (tid & 7)] = 0;
        if (tid == 0) xs[NN] = make_float2(0.f, 0.f);
    }
}

// ---------------- layer 1: aggregate xs [N,2] then transform by W1 ----------------
// stores h1 slab-major: h[(s*NSTR + node)*8 + f] for feat = s*8+f

__global__ __launch_bounds__(256) void k_layer1(const float2* __restrict__ xs,
        const int* __restrict__ rowptr, const int* __restrict__ col,
        const float* __restrict__ dis, const float* __restrict__ W1,
        const float* __restrict__ b1, u16* __restrict__ h1) {
    int tid = threadIdx.x, lane = tid & 63, wv = tid >> 6;
    int node = blockIdx.x * 4 + wv;
    if (node >= NN) return;
    int s = rowptr[node], e = rowptr[node + 1];
    float ax = 0.f, ay = 0.f;
    for (int base = s; base < e; base += 64) {
        int idx = base + lane;
        int cvr = col[idx];                 // safe overread (col +64 pad)
        int cv = (idx < e) ? cvr : NN;      // dummy xs[NN] = 0
        float2 xv = xs[cv];
        ax += xv.x; ay += xv.y;
    }
#pragma unroll
    for (int off = 32; off; off >>= 1) { ax += __shfl_xor(ax, off); ay += __shfl_xor(ay, off); }
    float dd = dis[node];
    ax *= dd; ay *= dd;
    float o = fmaxf(fmaf(ax, W1[lane], fmaf(ay, W1[HD + lane], b1[lane])), 0.f);
    *(u16*)((char*)h1 + ((size_t)((lane >> 3) * NSTR + node) * 16 + (lane & 7) * 2)) = f2b(o * dd);
}

// ---------------- transform: T = h @ W (both slab-major bf16) ----------------
// wave = 4 nodes; lane holds feat `lane` of its node (via one u64 slab-read);
// a_k broadcast by readlane; output written slab-major 2B/lane.

__global__ __launch_bounds__(256) void k_xf(const u16* __restrict__ hin,
        const float* __restrict__ W, u16* __restrict__ T) {
    int tid = threadIdx.x, lane = tid & 63, wv = tid >> 6;
    int n0 = blockIdx.x * 16 + wv * 4;
    int node = n0 + (lane >> 4);
    u64 v = *(const u64*)((const char*)hin +
            ((size_t)(((lane & 15) >> 1) * NSTR + node) * 16 + (size_t)(lane & 1) * 8));
    u32 lo = (u32)v, hi = (u32)(v >> 32);
    float hv[4] = { uaf(lo << 16), uaf(lo & 0xffff0000u), uaf(hi << 16), uaf(hi & 0xffff0000u) };
    float o[4] = {0.f, 0.f, 0.f, 0.f};
#pragma unroll
    for (int k = 0; k < HD; ++k) {
        float wk = W[k * HD + lane];
#pragma unroll
        for (int q = 0; q < 4; ++q) {
            float a = __int_as_float(__builtin_amdgcn_readlane(
                __float_as_int(hv[k & 3]), q * 16 + (k >> 2)));
            o[q] = fmaf(a, wk, o[q]);
        }
    }
    int js = lane >> 3, jf = lane & 7;
#pragma unroll
    for (int q = 0; q < 4; ++q)
        *(u16*)((char*)T + ((size_t)(js * NSTR + n0 + q) * 16 + jf * 2)) = f2b(o[q]);
}

// ---------------- slab-partitioned aggregation (XCD-pinned) ----------------
// slab = physical XCC_ID: this block only gathers its own 1.6MB slab of T -> L2-resident.
// Work distribution via per-slab batch queue (correct for ANY block->XCD mapping).
// out = relu(dis[d]*sum + b)  (* dis[d] again unless LAST), written slab-major.

template <bool LAST>
__global__ __launch_bounds__(256) void k_agg(const u16* __restrict__ T,
        const int* __restrict__ rowptr, const int* __restrict__ col,
        const float* __restrict__ dis, const float* __restrict__ b,
        u16* __restrict__ hout, int* __restrict__ queue) {
    __shared__ int sh_batch;
    int tid = threadIdx.x, lane = tid & 63, wv = tid >> 6;
    int q = lane >> 4, r = lane & 15, eslot = r >> 1, fh = lane & 1;
    int xcc;
    asm volatile("s_getreg_b32 %0, hwreg(20, 0, 32)" : "=s"(xcc));   // HW_REG_XCC_ID
    int slab = xcc & 7;
    const char* Tb = (const char*)(T + (size_t)slab * NSTR * 8);
    char* hb = (char*)(hout + (size_t)slab * NSTR * 8);
    float bb0 = b[slab * 8 + fh * 4 + 0];
    float bb1 = b[slab * 8 + fh * 4 + 1];
    float bb2 = b[slab * 8 + fh * 4 + 2];
    float bb3 = b[slab * 8 + fh * 4 + 3];
    for (;;) {
        __syncthreads();
        if (tid == 0) sh_batch = atomicAdd(&queue[slab * 64], 1);
        __syncthreads();
        int batch = sh_batch;
        if (batch >= NBATCH) break;
        int nb0 = batch * 256 + wv * 4 + q;
        for (int it = 0; it < 16; ++it) {
            int node = nb0 + it * 16;
            bool nv = node < NN;
            int s = nv ? rowptr[node] : 0;
            int e = nv ? rowptr[node + 1] : 0;
            float a0 = 0.f, a1 = 0.f, a2 = 0.f, a3 = 0.f;
            for (int base = s; base < e; base += 8) {
                int idx = base + eslot;
                int cvr = col[idx];                  // safe overread
                int cv = (idx < e) ? cvr : NN;       // dummy T row = 0
                u64 v = *(const u64*)(Tb + ((size_t)cv * 16 + (size_t)fh * 8));
                u32 lo = (u32)v, hi = (u32)(v >> 32);
                a0 += uaf(lo << 16); a1 += uaf(lo & 0xffff0000u);
                a2 += uaf(hi << 16); a3 += uaf(hi & 0xffff0000u);
            }
            a0 += __shfl_xor(a0, 2); a0 += __shfl_xor(a0, 4); a0 += __shfl_xor(a0, 8);
            a1 += __shfl_xor(a1, 2); a1 += __shfl_xor(a1, 4); a1 += __shfl_xor(a1, 8);
            a2 += __shfl_xor(a2, 2); a2 += __shfl_xor(a2, 4); a2 += __shfl_xor(a2, 8);
            a3 += __shfl_xor(a3, 2); a3 += __shfl_xor(a3, 4); a3 += __shfl_xor(a3, 8);
            if (nv && r < 2) {
                float dd = dis[node];
                float o0 = fmaxf(fmaf(dd, a0, bb0), 0.f);
                float o1 = fmaxf(fmaf(dd, a1, bb1), 0.f);
                float o2 = fmaxf(fmaf(dd, a2, bb2), 0.f);
                float o3 = fmaxf(fmaf(dd, a3, bb3), 0.f);
                if (!LAST) { o0 *= dd; o1 *= dd; o2 *= dd; o3 *= dd; }
                u64 wv64 = (u64)f2b(o0) | ((u64)f2b(o1) << 16) |
                           ((u64)f2b(o2) << 32) | ((u64)f2b(o3) << 48);
                *(u64*)(hb + ((size_t)node * 16 + (size_t)fh * 8)) = wv64;
            }
        }
    }
}

// ---------------- final: y = h3 @ Wl + bl (h3 slab-major) ----------------

__global__ __launch_bounds__(256) void k_final(const u16* __restrict__ h3,
        const float* __restrict__ Wl, const float* __restrict__ bl,
        float* __restrict__ y) {
    int tid = threadIdx.x, lane = tid & 63, wv = tid >> 6;
    int n0 = blockIdx.x * 16 + wv * 4;
    int node = n0 + (lane >> 4);
    u64 v = *(const u64*)((const char*)h3 +
            ((size_t)(((lane & 15) >> 1) * NSTR + node) * 16 + (size_t)(lane & 1) * 8));
    u32 lo = (u32)v, hi = (u32)(v >> 32);
    float4 wl = *(const float4*)(Wl + (lane & 15) * 4);
    float p = uaf(lo << 16) * wl.x + uaf(lo & 0xffff0000u) * wl.y
            + uaf(hi << 16) * wl.z + uaf(hi & 0xffff0000u) * wl.w;
    p += __shfl_xor(p, 1); p += __shfl_xor(p, 2);
    p += __shfl_xor(p, 4); p += __shfl_xor(p, 8);
    if ((lane & 15) == 0) y[node] = p + bl[0];
}

// ---------------- launch ----------------

extern "C" void kernel_launch(void* const* d_in, const int* in_sizes, int n_in,
                              void* d_out, int out_size, void* d_ws, size_t ws_size,
                              hipStream_t stream) {
    const float* x  = (const float*)d_in[0];
    const int*   ei = (const int*)d_in[1];   // [2,E]: src = ei[0:E], dst = ei[E:2E]
    const float* W1 = (const float*)d_in[2];
    const float* b1 = (const float*)d_in[3];
    const float* W2 = (const float*)d_in[4];
    const float* b2 = (const float*)d_in[5];
    const float* W3 = (const float*)d_in[6];
    const float* b3 = (const float*)d_in[7];
    const float* Wl = (const float*)d_in[8];
    const float* bl = (const float*)d_in[9];

    // workspace layout
    u32*    bins   = (u32*)d_ws;                          // NB*BCAP u32 (4.8 MB)
    float2* xs     = (float2*)(bins + (size_t)NB * BCAP); // NN+1
    int*    bfill  = (int*)(xs + (NN + 1));               // 128
    int*    cq     = bfill + 128;                         // 1024 (2 sets x 8 slabs x 64 stride)
    int*    rowptr = cq + 1024;                           // NN+2
    float*  dis    = (float*)(rowptr + (NN + 2));         // NN
    int*    col    = (int*)(dis + NN);                    // NE+NN+64 (overread pad)
    u16*    h1     = (u16*)(col + (NE + NN + 64));        // 8*NSTR*8 u16 (12.9 MB)
    u16*    h2     = h1 + (size_t)8 * NSTR * 8;
    u16*    T      = h2 + (size_t)8 * NSTR * 8;
    u16*    h3     = h1;                                  // alias: h1 dead after xf(h1)

    hipMemsetAsync(bfill, 0, (128 + 1024) * sizeof(int), stream);
    k_bin  <<<NB1, 256, 0, stream>>>(ei, bfill, bins);
    k_build<<<NB, 1024, 0, stream>>>(bins, bfill, rowptr, col,
                                     (const float2*)x, dis, xs, T);

    k_layer1<<<(NN + 3) / 4, 256, 0, stream>>>(xs, rowptr, col, dis, W1, b1, h1);

    k_xf <<<NN / 16, 256, 0, stream>>>(h1, W2, T);
    k_agg<false><<<2048, 256, 0, stream>>>(T, rowptr, col, dis, b2, h2, cq);

    k_xf <<<NN / 16, 256, 0, stream>>>(h2, W3, T);
    k_agg<true ><<<2048, 256, 0, stream>>>(T, rowptr, col, dis, b3, h3, cq + 512);

    k_final<<<NN / 16, 256, 0, stream>>>(h3, Wl, bl, (float*)d_out);
}

// Round 8
// 233.110 us; speedup vs baseline: 1.1741x; 1.1741x over previous
//
#include <hip/hip_runtime.h>
#include <hip/hip_bf16.h>

#define NN 100000
#define NE 1000000
#define HD 64
#define NB 98                       // dst buckets of 1024 nodes
#define BSH 10
#define BCAP 12288                  // bin capacity (avg 10240, +20 sigma)
#define EPB 8192                    // edges per k_bin block
#define NB1 ((NE + EPB - 1) / EPB)  // 123
#define NSL 4                       // feature slabs (16 feats = 32 B rows; 3.2 MB/slab)
#define NAGGB ((NN + 255) / 256)    // 391
#define NAGG (NSL * NAGGB)          // 1564

typedef unsigned short u16;
typedef unsigned int u32;
typedef unsigned long long u64;

__device__ __forceinline__ u16 f2b(float f) {
    __hip_bfloat16 h = __float2bfloat16(f);   // RNE
    return *reinterpret_cast<u16*>(&h);
}
__device__ __forceinline__ float uaf(u32 u) { return __uint_as_float(u); }
__device__ __forceinline__ void acc8(float* a, uint4 v) {
    a[0] += uaf(v.x << 16); a[1] += uaf(v.x & 0xffff0000u);
    a[2] += uaf(v.y << 16); a[3] += uaf(v.y & 0xffff0000u);
    a[4] += uaf(v.z << 16); a[5] += uaf(v.z & 0xffff0000u);
    a[6] += uaf(v.w << 16); a[7] += uaf(v.w & 0xffff0000u);
}

// ---------------- CSR build: bucketed counting sort (u32-packed bins) ----------------

__global__ __launch_bounds__(256) void k_bin(const int* __restrict__ ei,
                                             int* __restrict__ bfill,
                                             u32* __restrict__ bins) {
    __shared__ int hist[NB];
    __shared__ int base[NB];
    int tid = threadIdx.x;
    for (int i = tid; i < NB; i += 256) hist[i] = 0;
    __syncthreads();
    int e0 = blockIdx.x * EPB;
    int n = min(EPB, NE - e0);
    for (int i = tid; i < n; i += 256)
        atomicAdd(&hist[ei[NE + e0 + i] >> BSH], 1);
    __syncthreads();
    for (int i = tid; i < NB; i += 256) {
        int c = hist[i];
        base[i] = c ? atomicAdd(&bfill[i], c) : 0;
        hist[i] = 0;
    }
    __syncthreads();
    for (int i = tid; i < n; i += 256) {
        int s = ei[e0 + i];
        int d = ei[NE + e0 + i];
        int g = d >> BSH;
        int pos = base[g] + atomicAdd(&hist[g], 1);
        bins[(size_t)g * BCAP + min(pos, BCAP - 1)] = ((u32)(d & 1023) << 17) | (u32)s;
    }
}

// per bucket: base (from bfill), rowptr, self-loop, dis, xs, XCD-local edge scatter.
// Unpadded CSR: row len = cnt+1. col stores src INDEX.
__global__ __launch_bounds__(1024) void k_build(const u32* __restrict__ bins,
        const int* __restrict__ bfill,
        int* __restrict__ rowptr, int* __restrict__ col,
        const float2* __restrict__ x2, float* __restrict__ dis,
        float2* __restrict__ xs) {
    __shared__ int cnt[1024];
    __shared__ int rof[1024];
    __shared__ int wsum[16];
    __shared__ int gbase_sh;
    int g = blockIdx.x, tid = threadIdx.x;
    int lane = tid & 63, w = tid >> 6;

    // bucket base = sum_{t<g} (bfill[t] + 1024 self-loops)
    int part = (tid < g) ? (bfill[tid] + 1024) : 0;
#pragma unroll
    for (int off = 32; off; off >>= 1) part += __shfl_xor(part, off);
    if (lane == 0) wsum[w] = part;
    cnt[tid] = 0;
    __syncthreads();
    if (tid == 0) {
        int s = 0;
#pragma unroll
        for (int i = 0; i < 16; ++i) s += wsum[i];
        gbase_sh = s;
        if (g == NB - 1) rowptr[NN] = s + bfill[g] + (NN - (NB - 1) * 1024);
    }
    __syncthreads();
    int gbase = gbase_sh;

    int n = min(bfill[g], BCAP);
    const u32* bp = bins + (size_t)g * BCAP;
    for (int i = tid; i < n; i += 1024)
        atomicAdd(&cnt[bp[i] >> 17], 1);
    __syncthreads();

    int node = (g << BSH) + tid;
    int c = cnt[tid];
    int pc = (node < NN) ? (c + 1) : 0;

    int s = pc;
#pragma unroll
    for (int off = 1; off < 64; off <<= 1) { int t = __shfl_up(s, off); if (lane >= off) s += t; }
    if (lane == 63) wsum[w] = s;
    __syncthreads();
    if (tid < 16) {
        int ws = wsum[tid];
#pragma unroll
        for (int off = 1; off < 16; off <<= 1) { int t = __shfl_up(ws, off); if (tid >= off) ws += t; }
        wsum[tid] = ws;
    }
    __syncthreads();
    int r = gbase + (w ? wsum[w - 1] : 0) + s - pc;
    rof[tid] = r;
    if (node < NN) {
        rowptr[node] = r;
        col[r] = node;                    // self-loop at slot 0
        float dd = rsqrtf((float)(c + 1));
        dis[node] = dd;
        float2 xv = x2[node];
        xs[node] = make_float2(xv.x * dd, xv.y * dd);
    }
    cnt[tid] = 1;                         // fill counter (slot 0 taken)
    __syncthreads();

    for (int i = tid; i < n; i += 1024) {
        u32 v = bp[i];
        int dloc = v >> 17;
        int src = (int)(v & 0x1ffffu);
        int local = atomicAdd(&cnt[dloc], 1);
        col[rof[dloc] + local] = src;
    }

    if (g == 0 && tid == 0) xs[NN] = make_float2(0.f, 0.f);
}

// ---------------- layer 1: aggregate xs [N,2] then transform by W1 ----------------
// h layout (all h/T buffers): feat F of node n at byte ((F>>4)*NN + n)*32 + (F&15)*2

__global__ __launch_bounds__(256) void k_layer1(const float2* __restrict__ xs,
        const int* __restrict__ rowptr, const int* __restrict__ col,
        const float* __restrict__ dis, const float* __restrict__ W1,
        const float* __restrict__ b1, u16* __restrict__ h1) {
    int tid = threadIdx.x, lane = tid & 63, wv = tid >> 6;
    int node = blockIdx.x * 4 + wv;
    if (node >= NN) return;
    int s = rowptr[node], e = rowptr[node + 1];
    float ax = 0.f, ay = 0.f;
    for (int base = s; base < e; base += 64) {
        int idx = base + lane;
        int cvr = col[idx];                 // safe overread (col +64 pad)
        int cv = (idx < e) ? cvr : NN;      // dummy xs[NN] = 0
        float2 xv = xs[cv];
        ax += xv.x; ay += xv.y;
    }
#pragma unroll
    for (int off = 32; off; off >>= 1) { ax += __shfl_xor(ax, off); ay += __shfl_xor(ay, off); }
    float dd = dis[node];
    ax *= dd; ay *= dd;
    float o = fmaxf(fmaf(ax, W1[lane], fmaf(ay, W1[HD + lane], b1[lane])), 0.f);
    *(u16*)((char*)h1 + ((size_t)((lane >> 4) * NN + node) * 32 + (lane & 15) * 2)) = f2b(o * dd);
}

// ---------------- transform: T = h @ W (both slab-major bf16) ----------------
// wave = 4 nodes; lane holds feats 4*(lane&15)..+3 of node n0+(lane>>4) via one u64.

__global__ __launch_bounds__(256) void k_xf(const u16* __restrict__ hin,
        const float* __restrict__ W, u16* __restrict__ T) {
    int tid = threadIdx.x, lane = tid & 63, wv = tid >> 6;
    int n0 = blockIdx.x * 16 + wv * 4;
    int node = n0 + (lane >> 4);
    int fl = lane & 15;
    u64 v = *(const u64*)((const char*)hin +
            ((size_t)((fl >> 2) * NN + node) * 32 + (size_t)(fl & 3) * 8));
    u32 lo = (u32)v, hi = (u32)(v >> 32);
    float hv[4] = { uaf(lo << 16), uaf(lo & 0xffff0000u), uaf(hi << 16), uaf(hi & 0xffff0000u) };
    float o[4] = {0.f, 0.f, 0.f, 0.f};
#pragma unroll
    for (int k = 0; k < HD; ++k) {
        float wk = W[k * HD + lane];
#pragma unroll
        for (int q = 0; q < 4; ++q) {
            float a = __int_as_float(__builtin_amdgcn_readlane(
                __float_as_int(hv[k & 3]), q * 16 + (k >> 2)));
            o[q] = fmaf(a, wk, o[q]);
        }
    }
#pragma unroll
    for (int q = 0; q < 4; ++q)
        *(u16*)((char*)T + ((size_t)((lane >> 4) * NN + n0 + q) * 32 + (lane & 15) * 2)) = f2b(o[q]);
}

// ---------------- slab aggregation: one LANE per node ----------------
// slab = blockIdx&3 (static coverage; XCD affinity = natural round-robin, perf-only).
// 64 independent gather chains per wave, unrolled x2. Coalesced 32 B row writes.
// !LAST: hout = bf16(relu(dd*acc+b)*dd). LAST: partial[slab*NN+node] = relu(..)@Wl_slice

template <bool LAST>
__global__ __launch_bounds__(256) void k_agg(const u16* __restrict__ T,
        const int* __restrict__ rowptr, const int* __restrict__ col,
        const float* __restrict__ dis, const float* __restrict__ b,
        const float* __restrict__ Wl, u16* __restrict__ hout,
        float* __restrict__ partial) {
    int slab = blockIdx.x & 3;
    int node = (blockIdx.x >> 2) * 256 + threadIdx.x;
    if (node >= NN) return;
    const char* Tb = (const char*)T + (size_t)slab * NN * 32;

    int s = rowptr[node], e = rowptr[node + 1];   // >= 1 entry (self-loop)
    float acc[16];
#pragma unroll
    for (int j = 0; j < 16; ++j) acc[j] = 0.f;

    int i = s;
    for (; i + 2 <= e; i += 2) {
        int c0 = __builtin_nontemporal_load(col + i);
        int c1 = __builtin_nontemporal_load(col + i + 1);
        const uint4* r0 = (const uint4*)(Tb + (size_t)c0 * 32);
        const uint4* r1 = (const uint4*)(Tb + (size_t)c1 * 32);
        uint4 va0 = r0[0], va1 = r0[1];
        uint4 vb0 = r1[0], vb1 = r1[1];
        acc8(acc, va0); acc8(acc + 8, va1);
        acc8(acc, vb0); acc8(acc + 8, vb1);
    }
    if (i < e) {
        int c0 = __builtin_nontemporal_load(col + i);
        const uint4* r0 = (const uint4*)(Tb + (size_t)c0 * 32);
        uint4 va0 = r0[0], va1 = r0[1];
        acc8(acc, va0); acc8(acc + 8, va1);
    }

    float dd = dis[node];
    if (!LAST) {
        u32 p[8];
#pragma unroll
        for (int j = 0; j < 8; ++j) {
            float o0 = fmaxf(fmaf(dd, acc[2 * j],     b[slab * 16 + 2 * j]),     0.f) * dd;
            float o1 = fmaxf(fmaf(dd, acc[2 * j + 1], b[slab * 16 + 2 * j + 1]), 0.f) * dd;
            p[j] = (u32)f2b(o0) | ((u32)f2b(o1) << 16);
        }
        char* hb = (char*)hout + (size_t)(slab * (size_t)NN + node) * 32;
        *(uint4*)hb       = make_uint4(p[0], p[1], p[2], p[3]);
        *(uint4*)(hb + 16) = make_uint4(p[4], p[5], p[6], p[7]);
    } else {
        float ps = 0.f;
#pragma unroll
        for (int j = 0; j < 16; ++j)
            ps = fmaf(fmaxf(fmaf(dd, acc[j], b[slab * 16 + j]), 0.f),
                      Wl[slab * 16 + j], ps);
        partial[(size_t)slab * NN + node] = ps;
    }
}

// ---------------- final: y = sum of 4 slab partials + bl ----------------

__global__ __launch_bounds__(256) void k_fin(const float* __restrict__ partial,
        const float* __restrict__ bl, float* __restrict__ y) {
    int i = blockIdx.x * 256 + threadIdx.x;
    if (i >= NN) return;
    y[i] = partial[i] + partial[NN + i] + partial[2 * NN + i] + partial[3 * NN + i] + bl[0];
}

// ---------------- launch ----------------

extern "C" void kernel_launch(void* const* d_in, const int* in_sizes, int n_in,
                              void* d_out, int out_size, void* d_ws, size_t ws_size,
                              hipStream_t stream) {
    const float* x  = (const float*)d_in[0];
    const int*   ei = (const int*)d_in[1];   // [2,E]: src = ei[0:E], dst = ei[E:2E]
    const float* W1 = (const float*)d_in[2];
    const float* b1 = (const float*)d_in[3];
    const float* W2 = (const float*)d_in[4];
    const float* b2 = (const float*)d_in[5];
    const float* W3 = (const float*)d_in[6];
    const float* b3 = (const float*)d_in[7];
    const float* Wl = (const float*)d_in[8];
    const float* bl = (const float*)d_in[9];

    // workspace layout, 64 B aligned chunks
    char* p = (char*)d_ws;
    auto alloc = [&](size_t bytes) { char* r = p; p += (bytes + 63) & ~63ull; return r; };
    u32*    bins   = (u32*)   alloc((size_t)NB * BCAP * 4);
    int*    bfill  = (int*)   alloc(128 * 4);
    int*    rowptr = (int*)   alloc((NN + 2) * 4);
    float*  dis    = (float*) alloc(NN * 4);
    int*    col    = (int*)   alloc((NE + NN + 64) * 4);
    float2* xs     = (float2*)alloc((NN + 1) * 8);
    u16*    h1     = (u16*)   alloc((size_t)NN * HD * 2);
    u16*    h2     = (u16*)   alloc((size_t)NN * HD * 2);
    u16*    T      = (u16*)   alloc((size_t)NN * HD * 2);
    float*  partial= (float*) alloc((size_t)NSL * NN * 4);

    hipMemsetAsync(bfill, 0, 128 * sizeof(int), stream);
    k_bin  <<<NB1, 256, 0, stream>>>(ei, bfill, bins);
    k_build<<<NB, 1024, 0, stream>>>(bins, bfill, rowptr, col,
                                     (const float2*)x, dis, xs);

    k_layer1<<<(NN + 3) / 4, 256, 0, stream>>>(xs, rowptr, col, dis, W1, b1, h1);

    k_xf <<<NN / 16, 256, 0, stream>>>(h1, W2, T);
    k_agg<false><<<NAGG, 256, 0, stream>>>(T, rowptr, col, dis, b2, nullptr, h2, nullptr);

    k_xf <<<NN / 16, 256, 0, stream>>>(h2, W3, T);
    k_agg<true ><<<NAGG, 256, 0, stream>>>(T, rowptr, col, dis, b3, Wl, nullptr, partial);

    k_fin<<<(NN + 255) / 256, 256, 0, stream>>>(partial, bl, (float*)d_out);
}

// Round 9
// 197.259 us; speedup vs baseline: 1.3875x; 1.1817x over previous
//
#include <hip/hip_runtime.h>
#include <hip/hip_bf16.h>

#define NN 100000
#define NE 1000000
#define HD 64
#define NB 98                       // dst buckets of 1024 nodes
#define BSH 10
#define BCAP 12288                  // bin capacity (avg 10240, +20 sigma)
#define EPB 8192                    // edges per k_bin block
#define NB1 ((NE + EPB - 1) / EPB)  // 123
#define NSL 4                       // feature slabs (16 feats = 32 B rows)
#define RSTR (NN + 1)               // per-slab row stride (row NN = dummy zeros)
#define NAGGB ((NN + 255) / 256)    // 391
#define NAGG (NSL * NAGGB)          // 1564
#define BCAPP 4096                  // per-bucket pad slack (1024 self + 3*1024 pad max)

typedef unsigned short u16;
typedef unsigned int u32;
typedef unsigned long long u64;

__device__ __forceinline__ u16 f2b(float f) {
    __hip_bfloat16 h = __float2bfloat16(f);   // RNE
    return *reinterpret_cast<u16*>(&h);
}
__device__ __forceinline__ float uaf(u32 u) { return __uint_as_float(u); }
__device__ __forceinline__ void acc8(float* a, uint4 v) {
    a[0] += uaf(v.x << 16); a[1] += uaf(v.x & 0xffff0000u);
    a[2] += uaf(v.y << 16); a[3] += uaf(v.y & 0xffff0000u);
    a[4] += uaf(v.z << 16); a[5] += uaf(v.z & 0xffff0000u);
    a[6] += uaf(v.w << 16); a[7] += uaf(v.w & 0xffff0000u);
}

// ---------------- CSR build: bucketed counting sort (u32-packed bins) ----------------

__global__ __launch_bounds__(256) void k_bin(const int* __restrict__ ei,
                                             int* __restrict__ bfill,
                                             u32* __restrict__ bins) {
    __shared__ int hist[NB];
    __shared__ int base[NB];
    int tid = threadIdx.x;
    for (int i = tid; i < NB; i += 256) hist[i] = 0;
    __syncthreads();
    int e0 = blockIdx.x * EPB;
    int n = min(EPB, NE - e0);
    for (int i = tid; i < n; i += 256)
        atomicAdd(&hist[ei[NE + e0 + i] >> BSH], 1);
    __syncthreads();
    for (int i = tid; i < NB; i += 256) {
        int c = hist[i];
        base[i] = c ? atomicAdd(&bfill[i], c) : 0;
        hist[i] = 0;
    }
    __syncthreads();
    for (int i = tid; i < n; i += 256) {
        int s = ei[e0 + i];
        int d = ei[NE + e0 + i];
        int g = d >> BSH;
        int pos = base[g] + atomicAdd(&hist[g], 1);
        bins[(size_t)g * BCAP + min(pos, BCAP - 1)] = ((u32)(d & 1023) << 17) | (u32)s;
    }
}

// per bucket: rowptr (x4-aligned, padded rows), plen, self-loop+pads, dis, xs,
// XCD-local edge scatter, dummy-row zeroing. col stores src INDEX (pad = NN).
__global__ __launch_bounds__(1024) void k_build(const u32* __restrict__ bins,
        const int* __restrict__ bfill,
        int* __restrict__ rowptr, int* __restrict__ plen, int* __restrict__ col,
        const float2* __restrict__ x2, float* __restrict__ dis,
        float2* __restrict__ xs, u16* __restrict__ T) {
    __shared__ int cnt[1024];
    __shared__ int rof[1024];
    __shared__ int wsum[16];
    __shared__ int gbase_sh;
    int g = blockIdx.x, tid = threadIdx.x;
    int lane = tid & 63, w = tid >> 6;

    // bucket base = sum_{t<g} (align4(bfill[t]) + BCAPP)   (x4-aligned)
    int part = (tid < g) ? (((bfill[tid] + 3) & ~3) + BCAPP) : 0;
#pragma unroll
    for (int off = 32; off; off >>= 1) part += __shfl_xor(part, off);
    if (lane == 0) wsum[w] = part;
    cnt[tid] = 0;
    __syncthreads();
    if (tid == 0) {
        int s = 0;
#pragma unroll
        for (int i = 0; i < 16; ++i) s += wsum[i];
        gbase_sh = s;
    }
    __syncthreads();
    int gbase = gbase_sh;

    int n = min(bfill[g], BCAP);
    const u32* bp = bins + (size_t)g * BCAP;
    for (int i = tid; i < n; i += 1024)
        atomicAdd(&cnt[bp[i] >> 17], 1);
    __syncthreads();

    int node = (g << BSH) + tid;
    int c = cnt[tid];
    int pc = (node < NN) ? ((c + 1 + 3) & ~3) : 0;   // row len padded to x4

    int s = pc;
#pragma unroll
    for (int off = 1; off < 64; off <<= 1) { int t = __shfl_up(s, off); if (lane >= off) s += t; }
    if (lane == 63) wsum[w] = s;
    __syncthreads();
    if (tid < 16) {
        int ws = wsum[tid];
#pragma unroll
        for (int off = 1; off < 16; off <<= 1) { int t = __shfl_up(ws, off); if (tid >= off) ws += t; }
        wsum[tid] = ws;
    }
    __syncthreads();
    int r = gbase + (w ? wsum[w - 1] : 0) + s - pc;
    rof[tid] = r;
    if (node < NN) {
        rowptr[node] = r;
        plen[node] = pc;
        col[r] = node;                          // self-loop at slot 0
        for (int t = c + 1; t < pc; ++t) col[r + t] = NN;   // pads -> dummy row
        float dd = rsqrtf((float)(c + 1));
        dis[node] = dd;
        float2 xv = x2[node];
        xs[node] = make_float2(xv.x * dd, xv.y * dd);
    }
    cnt[tid] = 1;                               // fill counter (slot 0 taken)
    __syncthreads();

    for (int i = tid; i < n; i += 1024) {
        u32 v = bp[i];
        int dloc = v >> 17;
        int src = (int)(v & 0x1ffffu);
        int local = atomicAdd(&cnt[dloc], 1);
        col[rof[dloc] + local] = src;
    }

    if (g == 0) {
        // zero dummy row NN of each slab of T (u16 idx ((slab*RSTR)+NN)*16 + f)
        if (tid < NSL * 16) T[((size_t)(tid >> 4) * RSTR + NN) * 16 + (tid & 15)] = 0;
        if (tid == 0) xs[NN] = make_float2(0.f, 0.f);
    }
}

// ---------------- layer 1: aggregate xs [N,2] then transform by W1 ----------------
// h layout (h1/h2/T): feat F of node n at byte ((F>>4)*RSTR + n)*32 + (F&15)*2

__global__ __launch_bounds__(256) void k_layer1(const float2* __restrict__ xs,
        const int* __restrict__ rowptr, const int* __restrict__ plen,
        const int* __restrict__ col,
        const float* __restrict__ dis, const float* __restrict__ W1,
        const float* __restrict__ b1, u16* __restrict__ h1) {
    int tid = threadIdx.x, lane = tid & 63, wv = tid >> 6;
    int node = blockIdx.x * 4 + wv;
    if (node >= NN) return;
    int s = rowptr[node], e = s + plen[node];
    float ax = 0.f, ay = 0.f;
    for (int base = s; base < e; base += 64) {
        int idx = base + lane;
        int cvr = col[idx];                 // safe overread (col +64 pad)
        int cv = (idx < e) ? cvr : NN;      // dummy xs[NN] = 0 (pads also NN)
        float2 xv = xs[cv];
        ax += xv.x; ay += xv.y;
    }
#pragma unroll
    for (int off = 32; off; off >>= 1) { ax += __shfl_xor(ax, off); ay += __shfl_xor(ay, off); }
    float dd = dis[node];
    ax *= dd; ay *= dd;
    float o = fmaxf(fmaf(ax, W1[lane], fmaf(ay, W1[HD + lane], b1[lane])), 0.f);
    *(u16*)((char*)h1 + ((size_t)((lane >> 4) * RSTR + node) * 32 + (lane & 15) * 2)) = f2b(o * dd);
}

// ---------------- transform: T = h @ W (both slab-major bf16) ----------------

__global__ __launch_bounds__(256) void k_xf(const u16* __restrict__ hin,
        const float* __restrict__ W, u16* __restrict__ T) {
    int tid = threadIdx.x, lane = tid & 63, wv = tid >> 6;
    int n0 = blockIdx.x * 16 + wv * 4;
    int node = n0 + (lane >> 4);
    int fl = lane & 15;
    u64 v = *(const u64*)((const char*)hin +
            ((size_t)((fl >> 2) * RSTR + node) * 32 + (size_t)(fl & 3) * 8));
    u32 lo = (u32)v, hi = (u32)(v >> 32);
    float hv[4] = { uaf(lo << 16), uaf(lo & 0xffff0000u), uaf(hi << 16), uaf(hi & 0xffff0000u) };
    float o[4] = {0.f, 0.f, 0.f, 0.f};
#pragma unroll
    for (int k = 0; k < HD; ++k) {
        float wk = W[k * HD + lane];
#pragma unroll
        for (int q = 0; q < 4; ++q) {
            float a = __int_as_float(__builtin_amdgcn_readlane(
                __float_as_int(hv[k & 3]), q * 16 + (k >> 2)));
            o[q] = fmaf(a, wk, o[q]);
        }
    }
#pragma unroll
    for (int q = 0; q < 4; ++q)
        *(u16*)((char*)T + ((size_t)((lane >> 4) * RSTR + n0 + q) * 32 + (lane & 15) * 2)) = f2b(o[q]);
}

// ---------------- slab aggregation: one LANE per node, 16 gathers in flight ----------------
// slab = blockIdx&3 (XCD affinity via round-robin: slab served by 2 XCDs).
// Padded-x4 CSR: col for 8 edges = two int4 loads; 16 independent uint4 row-gathers.

template <bool LAST>
__global__ __launch_bounds__(256) void k_agg(const u16* __restrict__ T,
        const int* __restrict__ rowptr, const int* __restrict__ plen,
        const int* __restrict__ col,
        const float* __restrict__ dis, const float* __restrict__ b,
        const float* __restrict__ Wl, u16* __restrict__ hout,
        float* __restrict__ partial) {
    int slab = blockIdx.x & 3;
    int node = (blockIdx.x >> 2) * 256 + threadIdx.x;
    if (node >= NN) return;
    const char* Tb = (const char*)T + (size_t)slab * RSTR * 32;

    int r = rowptr[node];
    int pl = plen[node];                 // multiple of 4, >= 4
    float acc[16];
#pragma unroll
    for (int j = 0; j < 16; ++j) acc[j] = 0.f;

    int i = 0;
    for (; i + 8 <= pl; i += 8) {
        int4 c0 = *(const int4*)(col + r + i);
        int4 c1 = *(const int4*)(col + r + i + 4);
        const uint4* p0 = (const uint4*)(Tb + (size_t)c0.x * 32);
        const uint4* p1 = (const uint4*)(Tb + (size_t)c0.y * 32);
        const uint4* p2 = (const uint4*)(Tb + (size_t)c0.z * 32);
        const uint4* p3 = (const uint4*)(Tb + (size_t)c0.w * 32);
        const uint4* p4 = (const uint4*)(Tb + (size_t)c1.x * 32);
        const uint4* p5 = (const uint4*)(Tb + (size_t)c1.y * 32);
        const uint4* p6 = (const uint4*)(Tb + (size_t)c1.z * 32);
        const uint4* p7 = (const uint4*)(Tb + (size_t)c1.w * 32);
        uint4 v0a = p0[0], v0b = p0[1];
        uint4 v1a = p1[0], v1b = p1[1];
        uint4 v2a = p2[0], v2b = p2[1];
        uint4 v3a = p3[0], v3b = p3[1];
        uint4 v4a = p4[0], v4b = p4[1];
        uint4 v5a = p5[0], v5b = p5[1];
        uint4 v6a = p6[0], v6b = p6[1];
        uint4 v7a = p7[0], v7b = p7[1];
        acc8(acc, v0a); acc8(acc + 8, v0b);
        acc8(acc, v1a); acc8(acc + 8, v1b);
        acc8(acc, v2a); acc8(acc + 8, v2b);
        acc8(acc, v3a); acc8(acc + 8, v3b);
        acc8(acc, v4a); acc8(acc + 8, v4b);
        acc8(acc, v5a); acc8(acc + 8, v5b);
        acc8(acc, v6a); acc8(acc + 8, v6b);
        acc8(acc, v7a); acc8(acc + 8, v7b);
    }
    if (i < pl) {                        // exactly 4 remain
        int4 c0 = *(const int4*)(col + r + i);
        const uint4* p0 = (const uint4*)(Tb + (size_t)c0.x * 32);
        const uint4* p1 = (const uint4*)(Tb + (size_t)c0.y * 32);
        const uint4* p2 = (const uint4*)(Tb + (size_t)c0.z * 32);
        const uint4* p3 = (const uint4*)(Tb + (size_t)c0.w * 32);
        uint4 v0a = p0[0], v0b = p0[1];
        uint4 v1a = p1[0], v1b = p1[1];
        uint4 v2a = p2[0], v2b = p2[1];
        uint4 v3a = p3[0], v3b = p3[1];
        acc8(acc, v0a); acc8(acc + 8, v0b);
        acc8(acc, v1a); acc8(acc + 8, v1b);
        acc8(acc, v2a); acc8(acc + 8, v2b);
        acc8(acc, v3a); acc8(acc + 8, v3b);
    }

    float dd = dis[node];
    if (!LAST) {
        u32 p[8];
#pragma unroll
        for (int j = 0; j < 8; ++j) {
            float o0 = fmaxf(fmaf(dd, acc[2 * j],     b[slab * 16 + 2 * j]),     0.f) * dd;
            float o1 = fmaxf(fmaf(dd, acc[2 * j + 1], b[slab * 16 + 2 * j + 1]), 0.f) * dd;
            p[j] = (u32)f2b(o0) | ((u32)f2b(o1) << 16);
        }
        char* hb = (char*)hout + ((size_t)slab * RSTR + node) * 32;
        *(uint4*)hb        = make_uint4(p[0], p[1], p[2], p[3]);
        *(uint4*)(hb + 16) = make_uint4(p[4], p[5], p[6], p[7]);
    } else {
        float ps = 0.f;
#pragma unroll
        for (int j = 0; j < 16; ++j)
            ps = fmaf(fmaxf(fmaf(dd, acc[j], b[slab * 16 + j]), 0.f),
                      Wl[slab * 16 + j], ps);
        partial[(size_t)slab * NN + node] = ps;
    }
}

// ---------------- final: y = sum of 4 slab partials + bl ----------------

__global__ __launch_bounds__(256) void k_fin(const float* __restrict__ partial,
        const float* __restrict__ bl, float* __restrict__ y) {
    int i = blockIdx.x * 256 + threadIdx.x;
    if (i >= NN) return;
    y[i] = partial[i] + partial[NN + i] + partial[2 * NN + i] + partial[3 * NN + i] + bl[0];
}

// ---------------- launch ----------------

extern "C" void kernel_launch(void* const* d_in, const int* in_sizes, int n_in,
                              void* d_out, int out_size, void* d_ws, size_t ws_size,
                              hipStream_t stream) {
    const float* x  = (const float*)d_in[0];
    const int*   ei = (const int*)d_in[1];   // [2,E]: src = ei[0:E], dst = ei[E:2E]
    const float* W1 = (const float*)d_in[2];
    const float* b1 = (const float*)d_in[3];
    const float* W2 = (const float*)d_in[4];
    const float* b2 = (const float*)d_in[5];
    const float* W3 = (const float*)d_in[6];
    const float* b3 = (const float*)d_in[7];
    const float* Wl = (const float*)d_in[8];
    const float* bl = (const float*)d_in[9];

    // workspace layout, 64 B aligned chunks
    char* p = (char*)d_ws;
    auto alloc = [&](size_t bytes) { char* r = p; p += (bytes + 63) & ~63ull; return r; };
    u32*    bins   = (u32*)   alloc((size_t)NB * BCAP * 4);
    int*    bfill  = (int*)   alloc(128 * 4);
    int*    rowptr = (int*)   alloc((NN + 2) * 4);
    int*    plen   = (int*)   alloc((NN + 2) * 4);
    float*  dis    = (float*) alloc(NN * 4);
    int*    col    = (int*)   alloc((size_t)(NE + NB * BCAPP + 256) * 4);
    float2* xs     = (float2*)alloc((NN + 1) * 8);
    u16*    h1     = (u16*)   alloc((size_t)NSL * RSTR * 16 * 2);
    u16*    h2     = (u16*)   alloc((size_t)NSL * RSTR * 16 * 2);
    u16*    T      = (u16*)   alloc((size_t)NSL * RSTR * 16 * 2);
    float*  partial= (float*) alloc((size_t)NSL * NN * 4);

    hipMemsetAsync(bfill, 0, 128 * sizeof(int), stream);
    k_bin  <<<NB1, 256, 0, stream>>>(ei, bfill, bins);
    k_build<<<NB, 1024, 0, stream>>>(bins, bfill, rowptr, plen, col,
                                     (const float2*)x, dis, xs, T);

    k_layer1<<<(NN + 3) / 4, 256, 0, stream>>>(xs, rowptr, plen, col, dis, W1, b1, h1);

    k_xf <<<NN / 16, 256, 0, stream>>>(h1, W2, T);
    k_agg<false><<<NAGG, 256, 0, stream>>>(T, rowptr, plen, col, dis, b2, nullptr, h2, nullptr);

    k_xf <<<NN / 16, 256, 0, stream>>>(h2, W3, T);
    k_agg<true ><<<NAGG, 256, 0, stream>>>(T, rowptr, plen, col, dis, b3, Wl, nullptr, partial);

    k_fin<<<(NN + 255) / 256, 256, 0, stream>>>(partial, bl, (float*)d_out);
}